// Round 12
// baseline (281.072 us; speedup 1.0000x reference)
//
#include <hip/hip_runtime.h>

// ---------------- problem constants ----------------
// x:[N,128] W1:[128,128] b1:[128] W2:[128,64] b2:[64] edge_index:[2,E]
// out:[N,64] fp32. Intermediates bf16; GEMMs use bf16 MFMA (fp32 accum).
// CSR build: bucketed-partition chain (random writes stay line-local).
// Round-12: prefetch reverted (round-11 measured: miss-service-bound, not
// latency-bound). scanoff folded into partition (each block derives its own
// cursor column from raw h2; block 0 publishes coff); ccnt + memset deleted.
// 5 GPU ops: hist_wprep, partition, bucket_gemm(+gemm1), agg_gemm, agg2.

static constexpr int BSHIFT = 7;          // 128 node ids per coarse bucket
static constexpr int BWIDTH = 1 << BSHIFT;
static constexpr int MAXBUCK = 2048;      // supports N <= 262144 (pack needs N < 2^20)
static constexpr int NPART = 256;         // partition/hist grid size

// ---------------- workspace layout (bytes) ----------------
static constexpr size_t OFF_ROW  = 458752;    // u32[N+1]
static constexpr size_t OFF_COFF = 937984;    // u32[MAXBUCK+1]
static constexpr size_t OFF_DINV = 962560;    // f32[N]
static constexpr size_t OFF_CSR  = 1376256;   // i32[E]            (6.4 MB)
static constexpr size_t OFF_HS1  = 8388608;   // bf16[N*128] 25.6 MB
static constexpr size_t OFF_PART = 35651584;  // u32[E] 6.4 MB
static constexpr size_t OFF_HS2  = 62914560;  // bf16[N*64]  12.8 MB
static constexpr size_t OFF_H2   = 75714560;  // u32[MAXBUCK*NPART] (2 MB region)
static constexpr size_t OFF_W1S  = 77811712;  // bf16[128*128] swizzled (32 KB)
static constexpr size_t OFF_W2S  = 77844480;  // bf16[128*64]  swizzled (16 KB)

// ---------------- bf16 helpers ----------------
__device__ __forceinline__ unsigned short f2bf(float f) {  // RNE
    unsigned u = __float_as_uint(f);
    u += 0x7fffu + ((u >> 16) & 1u);
    return (unsigned short)(u >> 16);
}

typedef __attribute__((ext_vector_type(8))) short bf16x8;
typedef __attribute__((ext_vector_type(4))) float f32x4;

// ---------------- edge dtype self-detection ----------------
__device__ __forceinline__ unsigned detect_flag(const unsigned* __restrict__ w) {
    unsigned fl = 0;
#pragma unroll
    for (int k = 1; k < 32; k += 2) fl |= w[k];   // 16 wave-uniform loads
    return fl;
}

__device__ __forceinline__ int edge_dst(const unsigned* w, unsigned flag,
                                        int e, int E) {
    return flag ? (int)w[E + e] : (int)w[2 * E + 2 * e];
}
__device__ __forceinline__ int edge_src(const unsigned* w, unsigned flag,
                                        int e, int E) {
    return flag ? (int)w[e] : (int)w[2 * e];
}

// ---------------- pass A: coarse histogram + merged W pre-swizzle ----------
// Blocks [0,NPART): per-block bucket histogram of dst>>7 into h2 only.
__global__ __launch_bounds__(1024) void hist_wprep_kernel(
    const unsigned* __restrict__ w, unsigned* __restrict__ h2, int E,
    int nbuck, const float* __restrict__ W1, const float* __restrict__ W2,
    unsigned short* __restrict__ O1, unsigned short* __restrict__ O2) {
    if (blockIdx.x >= NPART) {   // ---- W prep ----
        const int which = blockIdx.x - NPART;
        const float* W = which ? W2 : W1;
        unsigned short* O = which ? O2 : O1;
        const int BN = which ? 64 : 128;
        const int total = 128 * BN / 4;
        for (int g = threadIdx.x; g < total; g += 1024) {
            int n = g % BN, k0 = (g / BN) * 4;
            ushort4 u;
            u.x = f2bf(W[(size_t)(k0 + 0) * BN + n]);
            u.y = f2bf(W[(size_t)(k0 + 1) * BN + n]);
            u.z = f2bf(W[(size_t)(k0 + 2) * BN + n]);
            u.w = f2bf(W[(size_t)(k0 + 3) * BN + n]);
            int off = ((((n >> 4) * 4 + (k0 >> 5)) * 16 + (n & 15)) * 4 +
                       ((k0 >> 3) & 3)) * 8 + (k0 & 4);
            *(ushort4*)(O + off) = u;
        }
        return;
    }
    __shared__ unsigned hist[MAXBUCK];
    for (int i = threadIdx.x; i < nbuck; i += 1024) hist[i] = 0;
    __syncthreads();
    const unsigned f = detect_flag(w);
    const int per = (E + NPART - 1) / NPART;
    const int e0 = blockIdx.x * per, e1 = min(E, e0 + per);
    for (int e = e0 + (int)threadIdx.x; e < e1; e += 1024)
        atomicAdd(&hist[edge_dst(w, f, e, E) >> BSHIFT], 1u);
    __syncthreads();
    for (int i = threadIdx.x; i < nbuck; i += 1024)
        h2[(size_t)i * NPART + blockIdx.x] = hist[i];
}

// ---------------- pass B: partition w/ self-derived cursors ----------------
// Each block reconstructs its own cursor column from raw h2:
//   lcur[i] = coff[i] + sum_{c<blk} h2[i][c];  coff = excl_scan(rowsum(h2)).
// Block 0 also publishes coff[] for bucket_gemm. Replaces the old scanoff
// dispatch (its output was consumed only here + coff).
// part entry = src | (dst&127)<<20  (valid: N < 2^20)
__global__ __launch_bounds__(1024) void partition_kernel(
    const unsigned* __restrict__ w, const unsigned* __restrict__ h2,
    unsigned* __restrict__ coff, unsigned* __restrict__ part, int E,
    int nbuck) {
    __shared__ unsigned lcur[MAXBUCK];   // column prefix, then cursor
    __shared__ unsigned tot[MAXBUCK];    // bucket totals
    __shared__ unsigned sh[1024];
    const int blk = blockIdx.x, t = threadIdx.x;
    // thread-per-bucket: stream the 256-col row; column prefix + total
    for (int i = t; i < nbuck; i += 1024) {
        const unsigned* hrow = h2 + (size_t)i * NPART;
        unsigned cs = 0, tt = 0;
        for (int c = 0; c < NPART; c++) {
            unsigned v = hrow[c];
            cs += (c < blk) ? v : 0u;
            tt += v;
        }
        lcur[i] = cs;
        tot[i] = tt;
    }
    __syncthreads();
    // exclusive scan of tot -> fold coff into lcur; block 0 publishes coff
    unsigned run = 0;
    for (int b0 = 0; b0 < nbuck; b0 += 1024) {
        unsigned v = (b0 + t < nbuck) ? tot[b0 + t] : 0u;
        sh[t] = v;
        __syncthreads();
        for (int off = 1; off < 1024; off <<= 1) {
            unsigned a = (t >= off) ? sh[t - off] : 0u;
            __syncthreads();
            sh[t] += a;
            __syncthreads();
        }
        if (b0 + t < nbuck) {
            unsigned coffb = run + sh[t] - v;
            lcur[b0 + t] += coffb;
            if (blk == 0) coff[b0 + t] = coffb;
        }
        run += sh[1023];
        __syncthreads();
    }
    if (blk == 0 && t == 0) coff[nbuck] = run;   // == E
    __syncthreads();
    // scatter edges through the block's private cursors
    const unsigned f = detect_flag(w);
    const int per = (E + NPART - 1) / NPART;
    const int e0 = blk * per, e1 = min(E, e0 + per);
    for (int e = e0 + t; e < e1; e += 1024) {
        int d = edge_dst(w, f, e, E);
        int s = edge_src(w, f, e, E);
        unsigned pos = atomicAdd(&lcur[d >> BSHIFT], 1u);
        part[pos] = (unsigned)s | ((unsigned)(d & (BWIDTH - 1)) << 20);
    }
}

// ---------------- LDS-free MFMA GEMM body (device fn) ----------------------
template <int BN, bool ABF16, bool SCALE>
__device__ __forceinline__ void gemm_body(
    const void* __restrict__ Av, const unsigned short* __restrict__ Bs,
    const float* __restrict__ dinv, unsigned short* __restrict__ out,
    int M, int row0, int t) {
    constexpr int NT = BN / 16;
    const int w = t >> 6, lane = t & 63;
    const int m = lane & 15, q = lane >> 4;
    const int fb = (m * 4 + q) * 8;

    const int r0 = row0 + (2 * w) * 16 + m;       // m-tile 2w
    const int r1 = r0 + 16;                        // m-tile 2w+1

    f32x4 acc[2][NT];
#pragma unroll
    for (int lt = 0; lt < 2; lt++)
#pragma unroll
        for (int nt = 0; nt < NT; nt++) acc[lt][nt] = (f32x4){0.f, 0.f, 0.f, 0.f};

#pragma unroll
    for (int ks = 0; ks < 4; ks++) {
        const int k0 = ks * 32 + q * 8;
        bf16x8 a0 = (bf16x8){0, 0, 0, 0, 0, 0, 0, 0};
        bf16x8 a1 = (bf16x8){0, 0, 0, 0, 0, 0, 0, 0};
        if (ABF16) {
            const unsigned short* A = (const unsigned short*)Av;
            if (r0 < M) a0 = *(const bf16x8*)(A + (size_t)r0 * 128 + k0);
            if (r1 < M) a1 = *(const bf16x8*)(A + (size_t)r1 * 128 + k0);
        } else {
            const float* A = (const float*)Av;
            if (r0 < M) {
                const float* p = A + (size_t)r0 * 128 + k0;
                f32x4 lo = *(const f32x4*)p, hi = *(const f32x4*)(p + 4);
                a0[0] = (short)f2bf(lo[0]); a0[1] = (short)f2bf(lo[1]);
                a0[2] = (short)f2bf(lo[2]); a0[3] = (short)f2bf(lo[3]);
                a0[4] = (short)f2bf(hi[0]); a0[5] = (short)f2bf(hi[1]);
                a0[6] = (short)f2bf(hi[2]); a0[7] = (short)f2bf(hi[3]);
            }
            if (r1 < M) {
                const float* p = A + (size_t)r1 * 128 + k0;
                f32x4 lo = *(const f32x4*)p, hi = *(const f32x4*)(p + 4);
                a1[0] = (short)f2bf(lo[0]); a1[1] = (short)f2bf(lo[1]);
                a1[2] = (short)f2bf(lo[2]); a1[3] = (short)f2bf(lo[3]);
                a1[4] = (short)f2bf(hi[0]); a1[5] = (short)f2bf(hi[1]);
                a1[6] = (short)f2bf(hi[2]); a1[7] = (short)f2bf(hi[3]);
            }
        }
#pragma unroll
        for (int nt = 0; nt < NT; nt++) {
            bf16x8 b = *(const bf16x8*)(Bs + (nt * 4 + ks) * 512 + fb);
            acc[0][nt] = __builtin_amdgcn_mfma_f32_16x16x32_bf16(a0, b, acc[0][nt], 0, 0, 0);
            acc[1][nt] = __builtin_amdgcn_mfma_f32_16x16x32_bf16(a1, b, acc[1][nt], 0, 0, 0);
        }
    }

#pragma unroll
    for (int lt = 0; lt < 2; lt++) {
#pragma unroll
        for (int r = 0; r < 4; r++) {
            int row = row0 + w * 32 + lt * 16 + q * 4 + r;
            if (row < M) {
                float s = SCALE ? dinv[row] : 1.0f;
#pragma unroll
                for (int nt = 0; nt < NT; nt++)
                    out[(size_t)row * BN + nt * 16 + m] = f2bf(acc[lt][nt][r] * s);
            }
        }
    }
}

// ---------------- pass C + gemm1 fused in one dispatch ---------------------
// Blocks [0,nbuck): per-bucket CSR + row + dinv (scans fused).
// Blocks [nbuck,..): gemm1 tiles, UNSCALED (dinv produced by sibling blocks;
// agg1 applies dinv[src] per edge instead).
__global__ __launch_bounds__(256, 4) void bucket_gemm_kernel(
    const unsigned* __restrict__ part, const unsigned* __restrict__ coff,
    unsigned* __restrict__ row, float* __restrict__ dinv,
    int* __restrict__ csr, int N, int nbuck,
    const float* __restrict__ x, const unsigned short* __restrict__ w1s,
    unsigned short* __restrict__ hs1) {
    __shared__ unsigned cnt[BWIDTH];
    __shared__ unsigned sc[BWIDTH];
    __shared__ unsigned cur[BWIDTH];
    const int bid = blockIdx.x, t = threadIdx.x;
    if (bid >= nbuck) {   // ---- gemm1 tile (no dinv read) ----
        gemm_body<128, false, false>(x, w1s, nullptr, hs1, N,
                                     (bid - nbuck) * 128, t);
        return;
    }
    const int b = bid, base = b << BSHIFT;
    if (t < BWIDTH) cnt[t] = 0;
    __syncthreads();
    const int e0 = (int)coff[b], e1 = (int)coff[b + 1];
    for (int e = e0 + t; e < e1; e += 256)
        atomicAdd(&cnt[part[e] >> 20], 1u);
    __syncthreads();
    if (t < BWIDTH) sc[t] = cnt[t];
    __syncthreads();
#pragma unroll
    for (int off = 1; off < BWIDTH; off <<= 1) {
        unsigned a = (t < BWIDTH && t >= off) ? sc[t - off] : 0u;
        __syncthreads();
        if (t < BWIDTH) sc[t] += a;
        __syncthreads();
    }
    if (t < BWIDTH) {
        unsigned r = (unsigned)e0 + sc[t] - cnt[t];   // row[base+t]
        cur[t] = r;
        if (base + t < N) {
            row[base + t] = r;
            dinv[base + t] = rsqrtf((float)cnt[t] + 1.0f);
        }
    }
    if (t == 0 && b == nbuck - 1) row[N] = (unsigned)e1;  // == E
    __syncthreads();
    for (int e = e0 + t; e < e1; e += 256) {
        unsigned pk = part[e];
        unsigned p = atomicAdd(&cur[pk >> 20], 1u);
        csr[p] = (int)(pk & 0xFFFFFu);
    }
}

// ---------------- fused agg1 + gemm2 (round-10 proven bodies) --------------
__global__ __launch_bounds__(256) void agg_gemm_kernel(
    const int* __restrict__ csr, const unsigned* __restrict__ row,
    const unsigned short* __restrict__ hs1, const float* __restrict__ dinv,
    const float* __restrict__ bias, const unsigned short* __restrict__ w2s,
    unsigned short* __restrict__ hs2, int N) {
    __shared__ short sA[2048];   // 16 rows x 128 ch, frag order
    const int t = threadIdx.x;
    const int i0 = blockIdx.x * 16;
    const int i = i0 + (t >> 4);   // node
    const int l = t & 15;          // channel-lane: ch [8l, 8l+8)

    float s0 = 0.f, s1 = 0.f, s2 = 0.f, s3 = 0.f,
          s4 = 0.f, s5 = 0.f, s6 = 0.f, s7 = 0.f;
    if (i < N) {
        const int co = 8 * l;
        {
            const float wsf = dinv[i];
            uint4 u = *(const uint4*)(hs1 + (size_t)i * 128 + co);   // self
            s0 += wsf * __uint_as_float(u.x << 16);
            s1 += wsf * __uint_as_float(u.x & 0xffff0000u);
            s2 += wsf * __uint_as_float(u.y << 16);
            s3 += wsf * __uint_as_float(u.y & 0xffff0000u);
            s4 += wsf * __uint_as_float(u.z << 16);
            s5 += wsf * __uint_as_float(u.z & 0xffff0000u);
            s6 += wsf * __uint_as_float(u.w << 16);
            s7 += wsf * __uint_as_float(u.w & 0xffff0000u);
        }
        const int rs = (int)row[i], re = (int)row[i + 1];
        for (int e0 = rs; e0 < re; e0 += 16) {
            int idx = (e0 + l < re) ? csr[e0 + l] : 0;
            const int cnt = min(16, re - e0);
#pragma unroll 4
            for (int j = 0; j < cnt; j++) {
                int s = __shfl(idx, j, 16);
                const float wsr = dinv[s];
                uint4 u = *(const uint4*)(hs1 + (size_t)s * 128 + co);
                s0 += wsr * __uint_as_float(u.x << 16);
                s1 += wsr * __uint_as_float(u.x & 0xffff0000u);
                s2 += wsr * __uint_as_float(u.y << 16);
                s3 += wsr * __uint_as_float(u.y & 0xffff0000u);
                s4 += wsr * __uint_as_float(u.z << 16);
                s5 += wsr * __uint_as_float(u.z & 0xffff0000u);
                s6 += wsr * __uint_as_float(u.w << 16);
                s7 += wsr * __uint_as_float(u.w & 0xffff0000u);
            }
        }
        const float sc = dinv[i];
        const int co2 = 8 * l;
        const float4 ba = *(const float4*)(bias + co2);
        const float4 bb = *(const float4*)(bias + co2 + 4);
        s0 = fmaxf(s0 * sc + ba.x, 0.f); s1 = fmaxf(s1 * sc + ba.y, 0.f);
        s2 = fmaxf(s2 * sc + ba.z, 0.f); s3 = fmaxf(s3 * sc + ba.w, 0.f);
        s4 = fmaxf(s4 * sc + bb.x, 0.f); s5 = fmaxf(s5 * sc + bb.y, 0.f);
        s6 = fmaxf(s6 * sc + bb.z, 0.f); s7 = fmaxf(s7 * sc + bb.w, 0.f);
    } else {
        s0 = s1 = s2 = s3 = s4 = s5 = s6 = s7 = 0.f;
    }
    // ---- pack bf16 + store to LDS in A-frag order ----
    {
        uint4 u;
        u.x = (unsigned)f2bf(s0) | ((unsigned)f2bf(s1) << 16);
        u.y = (unsigned)f2bf(s2) | ((unsigned)f2bf(s3) << 16);
        u.z = (unsigned)f2bf(s4) | ((unsigned)f2bf(s5) << 16);
        u.w = (unsigned)f2bf(s6) | ((unsigned)f2bf(s7) << 16);
        int off = (l >> 2) * 512 + (((t >> 4) * 4 + (l & 3)) * 8);
        *(uint4*)(sA + off) = u;
    }
    __syncthreads();

    // ---- gemm phase: wave w computes n-tile nt=w (cols [16w,16w+16)) ----
    const int w = t >> 6, lane = t & 63;
    const int m = lane & 15, q = lane >> 4;
    const int fb = (m * 4 + q) * 8;
    f32x4 acc = (f32x4){0.f, 0.f, 0.f, 0.f};
#pragma unroll
    for (int ks = 0; ks < 4; ks++) {
        bf16x8 a = *(const bf16x8*)(sA + ks * 512 + fb);
        bf16x8 b = *(const bf16x8*)(w2s + (w * 4 + ks) * 512 + fb);
        acc = __builtin_amdgcn_mfma_f32_16x16x32_bf16(a, b, acc, 0, 0, 0);
    }
    // D layout: row = q*4+r (node within tile), col = w*16 + m
#pragma unroll
    for (int r = 0; r < 4; r++) {
        int rr = i0 + q * 4 + r;
        if (rr < N) {
            float s = dinv[rr];
            hs2[(size_t)rr * 64 + w * 16 + m] = f2bf(acc[r] * s);
        }
    }
}

// ---------------- agg2 (round-10 proven, scaled inputs, fp32 out) ----------
__global__ __launch_bounds__(256) void agg2_kernel(
    const int* __restrict__ csr, const unsigned* __restrict__ row,
    const unsigned short* __restrict__ hsb, const float* __restrict__ dinv,
    const float* __restrict__ bias, float* __restrict__ outv, int N) {
    constexpr int C = 64, LPN = 8;
    const int tid = blockIdx.x * 256 + threadIdx.x;
    const int i = tid / LPN;
    const int l = tid % LPN;
    if (i >= N) return;

    const int co = 8 * l;
    float s0 = 0.f, s1 = 0.f, s2 = 0.f, s3 = 0.f,
          s4 = 0.f, s5 = 0.f, s6 = 0.f, s7 = 0.f;
    {
        uint4 u = *(const uint4*)(hsb + (size_t)i * C + co);   // self
        s0 += __uint_as_float(u.x << 16); s1 += __uint_as_float(u.x & 0xffff0000u);
        s2 += __uint_as_float(u.y << 16); s3 += __uint_as_float(u.y & 0xffff0000u);
        s4 += __uint_as_float(u.z << 16); s5 += __uint_as_float(u.z & 0xffff0000u);
        s6 += __uint_as_float(u.w << 16); s7 += __uint_as_float(u.w & 0xffff0000u);
    }

    const int rs = (int)row[i], re = (int)row[i + 1];
    for (int e0 = rs; e0 < re; e0 += LPN) {
        int idx = (e0 + l < re) ? csr[e0 + l] : 0;
        const int cnt = min(LPN, re - e0);
#pragma unroll 4
        for (int j = 0; j < cnt; j++) {
            int s = __shfl(idx, j, LPN);
            uint4 u = *(const uint4*)(hsb + (size_t)s * C + co);
            s0 += __uint_as_float(u.x << 16); s1 += __uint_as_float(u.x & 0xffff0000u);
            s2 += __uint_as_float(u.y << 16); s3 += __uint_as_float(u.y & 0xffff0000u);
            s4 += __uint_as_float(u.z << 16); s5 += __uint_as_float(u.z & 0xffff0000u);
            s6 += __uint_as_float(u.w << 16); s7 += __uint_as_float(u.w & 0xffff0000u);
        }
    }

    const float sc = dinv[i];
    const float4 ba = *(const float4*)(bias + co);
    const float4 bb = *(const float4*)(bias + co + 4);
    float4 a = make_float4(s0 * sc + ba.x, s1 * sc + ba.y,
                           s2 * sc + ba.z, s3 * sc + ba.w);
    float4 b = make_float4(s4 * sc + bb.x, s5 * sc + bb.y,
                           s6 * sc + bb.z, s7 * sc + bb.w);
    *(float4*)(outv + (size_t)i * C + co) = a;
    *(float4*)(outv + (size_t)i * C + co + 4) = b;
}

// ---------------- launch ----------------
extern "C" void kernel_launch(void* const* d_in, const int* in_sizes, int n_in,
                              void* d_out, int out_size, void* d_ws,
                              size_t ws_size, hipStream_t stream) {
    const float* x  = (const float*)d_in[0];
    const float* W1 = (const float*)d_in[1];
    const float* b1 = (const float*)d_in[2];
    const float* W2 = (const float*)d_in[3];
    const float* b2 = (const float*)d_in[4];
    const unsigned* ew = (const unsigned*)d_in[5];
    const int E = in_sizes[5] / 2;        // 1,600,000
    const int N = in_sizes[0] / 128;      // 100,000
    const int nbuck = (N + BWIDTH - 1) >> BSHIFT;   // 782

    char* ws = (char*)d_ws;
    unsigned* row  = (unsigned*)(ws + OFF_ROW);
    unsigned* coff = (unsigned*)(ws + OFF_COFF);
    float* dinv    = (float*)(ws + OFF_DINV);
    int* csr       = (int*)(ws + OFF_CSR);
    unsigned short* hs1  = (unsigned short*)(ws + OFF_HS1);
    unsigned short* hs2  = (unsigned short*)(ws + OFF_HS2);
    unsigned* h2   = (unsigned*)(ws + OFF_H2);
    unsigned short* w1s  = (unsigned short*)(ws + OFF_W1S);
    unsigned short* w2s  = (unsigned short*)(ws + OFF_W2S);
    unsigned* part = (unsigned*)(ws + OFF_PART);

    // ---- CSR build + W prep (no memset needed: h2 fully overwritten) ----
    hist_wprep_kernel<<<NPART + 2, 1024, 0, stream>>>(ew, h2, E, nbuck,
                                                      W1, W2, w1s, w2s);
    partition_kernel<<<NPART, 1024, 0, stream>>>(ew, h2, coff, part, E, nbuck);
    bucket_gemm_kernel<<<nbuck + (N + 127) / 128, 256, 0, stream>>>(
        part, coff, row, dinv, csr, N, nbuck, x, w1s, hs1);

    // ---- fused agg1 + gemm2 ----
    agg_gemm_kernel<<<(N + 15) / 16, 256, 0, stream>>>(
        csr, row, hs1, dinv, b1, w2s, hs2, N);

    // ---- agg2 (final, fp32 out) ----
    agg2_kernel<<<(N * 8 + 255) / 256, 256, 0, stream>>>(
        csr, row, hs2, dinv, b2, (float*)d_out, N);
}

// Round 13
// 264.729 us; speedup vs baseline: 1.0617x; 1.0617x over previous
//
#include <hip/hip_runtime.h>

// ---------------- problem constants ----------------
// x:[N,128] W1:[128,128] b1:[128] W2:[128,64] b2:[64] edge_index:[2,E]
// out:[N,64] fp32. Intermediates bf16; GEMMs use bf16 MFMA (fp32 accum).
// CSR build: bucketed-partition chain (random writes stay line-local).
// Round-13: full revert to round-10 (best, 267.9 us; rounds 11/12 both
// regressed and were reverted per pre-registered failure signatures),
// plus one isolated zero-risk tweak: NT store of the final fp32 output
// (write-once stream; avoids evicting the hs2 gather table from L2).
// 7 GPU ops: memset, hist_wprep, scanoff, partition, bucket_gemm(+gemm1),
// agg_gemm(agg1+gemm2), agg2.

static constexpr int BSHIFT = 7;          // 128 node ids per coarse bucket
static constexpr int BWIDTH = 1 << BSHIFT;
static constexpr int MAXBUCK = 2048;      // supports N <= 262144 (pack needs N < 2^20)
static constexpr int NPART = 256;         // partition/hist grid size

// ---------------- workspace layout (bytes) ----------------
static constexpr size_t OFF_ROW  = 458752;    // u32[N+1]
static constexpr size_t OFF_CCNT = 925696;    // u32[MAXBUCK+1]
static constexpr size_t OFF_COFF = 937984;    // u32[MAXBUCK+1]
static constexpr size_t OFF_DINV = 962560;    // f32[N]
static constexpr size_t OFF_CSR  = 1376256;   // i32[E]            (6.4 MB)
static constexpr size_t OFF_HS1  = 8388608;   // bf16[N*128] 25.6 MB
static constexpr size_t OFF_PART = 35651584;  // u32[E] 6.4 MB
static constexpr size_t OFF_HS2  = 62914560;  // bf16[N*64]  12.8 MB
static constexpr size_t OFF_H2   = 75714560;  // u32[MAXBUCK*NPART] (2 MB region)
static constexpr size_t OFF_W1S  = 77811712;  // bf16[128*128] swizzled (32 KB)
static constexpr size_t OFF_W2S  = 77844480;  // bf16[128*64]  swizzled (16 KB)

// ---------------- bf16 helpers ----------------
__device__ __forceinline__ unsigned short f2bf(float f) {  // RNE
    unsigned u = __float_as_uint(f);
    u += 0x7fffu + ((u >> 16) & 1u);
    return (unsigned short)(u >> 16);
}

typedef __attribute__((ext_vector_type(8))) short bf16x8;
typedef __attribute__((ext_vector_type(4))) float f32x4;

// ---------------- edge dtype self-detection ----------------
__device__ __forceinline__ unsigned detect_flag(const unsigned* __restrict__ w) {
    unsigned fl = 0;
#pragma unroll
    for (int k = 1; k < 32; k += 2) fl |= w[k];   // 16 wave-uniform loads
    return fl;
}

__device__ __forceinline__ int edge_dst(const unsigned* w, unsigned flag,
                                        int e, int E) {
    return flag ? (int)w[E + e] : (int)w[2 * E + 2 * e];
}
__device__ __forceinline__ int edge_src(const unsigned* w, unsigned flag,
                                        int e, int E) {
    return flag ? (int)w[e] : (int)w[2 * e];
}

// ---------------- pass A: coarse histogram + merged W pre-swizzle ----------
__global__ __launch_bounds__(1024) void hist_wprep_kernel(
    const unsigned* __restrict__ w, unsigned* __restrict__ ccnt,
    unsigned* __restrict__ h2, int E, int nbuck,
    const float* __restrict__ W1, const float* __restrict__ W2,
    unsigned short* __restrict__ O1, unsigned short* __restrict__ O2) {
    if (blockIdx.x >= NPART) {   // ---- W prep ----
        const int which = blockIdx.x - NPART;
        const float* W = which ? W2 : W1;
        unsigned short* O = which ? O2 : O1;
        const int BN = which ? 64 : 128;
        const int total = 128 * BN / 4;
        for (int g = threadIdx.x; g < total; g += 1024) {
            int n = g % BN, k0 = (g / BN) * 4;
            ushort4 u;
            u.x = f2bf(W[(size_t)(k0 + 0) * BN + n]);
            u.y = f2bf(W[(size_t)(k0 + 1) * BN + n]);
            u.z = f2bf(W[(size_t)(k0 + 2) * BN + n]);
            u.w = f2bf(W[(size_t)(k0 + 3) * BN + n]);
            int off = ((((n >> 4) * 4 + (k0 >> 5)) * 16 + (n & 15)) * 4 +
                       ((k0 >> 3) & 3)) * 8 + (k0 & 4);
            *(ushort4*)(O + off) = u;
        }
        return;
    }
    __shared__ unsigned hist[MAXBUCK];
    for (int i = threadIdx.x; i < nbuck; i += 1024) hist[i] = 0;
    __syncthreads();
    const unsigned f = detect_flag(w);
    const int per = (E + NPART - 1) / NPART;
    const int e0 = blockIdx.x * per, e1 = min(E, e0 + per);
    for (int e = e0 + (int)threadIdx.x; e < e1; e += 1024)
        atomicAdd(&hist[edge_dst(w, f, e, E) >> BSHIFT], 1u);
    __syncthreads();
    for (int i = threadIdx.x; i < nbuck; i += 1024) {
        unsigned h = hist[i];
        h2[(size_t)i * NPART + blockIdx.x] = h;
        if (h) atomicAdd(&ccnt[i], h);
    }
}

// ---------------- merged coarse scan + off2d --------------------------------
__global__ __launch_bounds__(NPART) void scanoff_kernel(
    const unsigned* __restrict__ ccnt, unsigned* __restrict__ coff,
    unsigned* __restrict__ h2, int nbuck) {
    __shared__ unsigned red[NPART];
    __shared__ unsigned sh[NPART];
    const int b = blockIdx.x, t = threadIdx.x;
    unsigned p = 0;
    for (int i = t; i < b; i += NPART) p += ccnt[i];
    red[t] = p;
    __syncthreads();
#pragma unroll
    for (int off = NPART / 2; off > 0; off >>= 1) {
        if (t < off) red[t] += red[t + off];
        __syncthreads();
    }
    const unsigned coffb = red[0];
    if (t == 0) {
        coff[b] = coffb;
        if (b == nbuck - 1) coff[nbuck] = coffb + ccnt[b];
    }
    unsigned v = h2[(size_t)b * NPART + t];
    sh[t] = v;
    __syncthreads();
#pragma unroll
    for (int off = 1; off < NPART; off <<= 1) {
        unsigned a = (t >= off) ? sh[t - off] : 0u;
        __syncthreads();
        sh[t] += a;
        __syncthreads();
    }
    h2[(size_t)b * NPART + t] = coffb + sh[t] - v;   // exclusive + base
}

// ---------------- pass B: partition (packed 4 B entries) ----------------
// part entry = src | (dst&127)<<20  (valid: N < 2^20)
__global__ __launch_bounds__(1024) void partition_kernel(
    const unsigned* __restrict__ w, const unsigned* __restrict__ h2,
    unsigned* __restrict__ part, int E, int nbuck) {
    __shared__ unsigned lcur[MAXBUCK];
    for (int i = threadIdx.x; i < nbuck; i += 1024)
        lcur[i] = h2[(size_t)i * NPART + blockIdx.x];
    __syncthreads();
    const unsigned f = detect_flag(w);
    const int per = (E + NPART - 1) / NPART;
    const int e0 = blockIdx.x * per, e1 = min(E, e0 + per);
    for (int e = e0 + (int)threadIdx.x; e < e1; e += 1024) {
        int d = edge_dst(w, f, e, E);
        int s = edge_src(w, f, e, E);
        unsigned pos = atomicAdd(&lcur[d >> BSHIFT], 1u);
        part[pos] = (unsigned)s | ((unsigned)(d & (BWIDTH - 1)) << 20);
    }
}

// ---------------- LDS-free MFMA GEMM body (device fn) ----------------------
template <int BN, bool ABF16, bool SCALE>
__device__ __forceinline__ void gemm_body(
    const void* __restrict__ Av, const unsigned short* __restrict__ Bs,
    const float* __restrict__ dinv, unsigned short* __restrict__ out,
    int M, int row0, int t) {
    constexpr int NT = BN / 16;
    const int w = t >> 6, lane = t & 63;
    const int m = lane & 15, q = lane >> 4;
    const int fb = (m * 4 + q) * 8;

    const int r0 = row0 + (2 * w) * 16 + m;       // m-tile 2w
    const int r1 = r0 + 16;                        // m-tile 2w+1

    f32x4 acc[2][NT];
#pragma unroll
    for (int lt = 0; lt < 2; lt++)
#pragma unroll
        for (int nt = 0; nt < NT; nt++) acc[lt][nt] = (f32x4){0.f, 0.f, 0.f, 0.f};

#pragma unroll
    for (int ks = 0; ks < 4; ks++) {
        const int k0 = ks * 32 + q * 8;
        bf16x8 a0 = (bf16x8){0, 0, 0, 0, 0, 0, 0, 0};
        bf16x8 a1 = (bf16x8){0, 0, 0, 0, 0, 0, 0, 0};
        if (ABF16) {
            const unsigned short* A = (const unsigned short*)Av;
            if (r0 < M) a0 = *(const bf16x8*)(A + (size_t)r0 * 128 + k0);
            if (r1 < M) a1 = *(const bf16x8*)(A + (size_t)r1 * 128 + k0);
        } else {
            const float* A = (const float*)Av;
            if (r0 < M) {
                const float* p = A + (size_t)r0 * 128 + k0;
                f32x4 lo = *(const f32x4*)p, hi = *(const f32x4*)(p + 4);
                a0[0] = (short)f2bf(lo[0]); a0[1] = (short)f2bf(lo[1]);
                a0[2] = (short)f2bf(lo[2]); a0[3] = (short)f2bf(lo[3]);
                a0[4] = (short)f2bf(hi[0]); a0[5] = (short)f2bf(hi[1]);
                a0[6] = (short)f2bf(hi[2]); a0[7] = (short)f2bf(hi[3]);
            }
            if (r1 < M) {
                const float* p = A + (size_t)r1 * 128 + k0;
                f32x4 lo = *(const f32x4*)p, hi = *(const f32x4*)(p + 4);
                a1[0] = (short)f2bf(lo[0]); a1[1] = (short)f2bf(lo[1]);
                a1[2] = (short)f2bf(lo[2]); a1[3] = (short)f2bf(lo[3]);
                a1[4] = (short)f2bf(hi[0]); a1[5] = (short)f2bf(hi[1]);
                a1[6] = (short)f2bf(hi[2]); a1[7] = (short)f2bf(hi[3]);
            }
        }
#pragma unroll
        for (int nt = 0; nt < NT; nt++) {
            bf16x8 b = *(const bf16x8*)(Bs + (nt * 4 + ks) * 512 + fb);
            acc[0][nt] = __builtin_amdgcn_mfma_f32_16x16x32_bf16(a0, b, acc[0][nt], 0, 0, 0);
            acc[1][nt] = __builtin_amdgcn_mfma_f32_16x16x32_bf16(a1, b, acc[1][nt], 0, 0, 0);
        }
    }

#pragma unroll
    for (int lt = 0; lt < 2; lt++) {
#pragma unroll
        for (int r = 0; r < 4; r++) {
            int row = row0 + w * 32 + lt * 16 + q * 4 + r;
            if (row < M) {
                float s = SCALE ? dinv[row] : 1.0f;
#pragma unroll
                for (int nt = 0; nt < NT; nt++)
                    out[(size_t)row * BN + nt * 16 + m] = f2bf(acc[lt][nt][r] * s);
            }
        }
    }
}

// ---------------- pass C + gemm1 fused in one dispatch ---------------------
// Blocks [0,nbuck): per-bucket CSR + row + dinv (scans fused).
// Blocks [nbuck,..): gemm1 tiles, UNSCALED (dinv produced by sibling blocks;
// agg1 applies dinv[src] per edge instead).
__global__ __launch_bounds__(256, 4) void bucket_gemm_kernel(
    const unsigned* __restrict__ part, const unsigned* __restrict__ coff,
    unsigned* __restrict__ row, float* __restrict__ dinv,
    int* __restrict__ csr, int N, int nbuck,
    const float* __restrict__ x, const unsigned short* __restrict__ w1s,
    unsigned short* __restrict__ hs1) {
    __shared__ unsigned cnt[BWIDTH];
    __shared__ unsigned sc[BWIDTH];
    __shared__ unsigned cur[BWIDTH];
    const int bid = blockIdx.x, t = threadIdx.x;
    if (bid >= nbuck) {   // ---- gemm1 tile (no dinv read) ----
        gemm_body<128, false, false>(x, w1s, nullptr, hs1, N,
                                     (bid - nbuck) * 128, t);
        return;
    }
    const int b = bid, base = b << BSHIFT;
    if (t < BWIDTH) cnt[t] = 0;
    __syncthreads();
    const int e0 = (int)coff[b], e1 = (int)coff[b + 1];
    for (int e = e0 + t; e < e1; e += 256)
        atomicAdd(&cnt[part[e] >> 20], 1u);
    __syncthreads();
    if (t < BWIDTH) sc[t] = cnt[t];
    __syncthreads();
#pragma unroll
    for (int off = 1; off < BWIDTH; off <<= 1) {
        unsigned a = (t < BWIDTH && t >= off) ? sc[t - off] : 0u;
        __syncthreads();
        if (t < BWIDTH) sc[t] += a;
        __syncthreads();
    }
    if (t < BWIDTH) {
        unsigned r = (unsigned)e0 + sc[t] - cnt[t];   // row[base+t]
        cur[t] = r;
        if (base + t < N) {
            row[base + t] = r;
            dinv[base + t] = rsqrtf((float)cnt[t] + 1.0f);
        }
    }
    if (t == 0 && b == nbuck - 1) row[N] = (unsigned)e1;  // == E
    __syncthreads();
    for (int e = e0 + t; e < e1; e += 256) {
        unsigned pk = part[e];
        unsigned p = atomicAdd(&cur[pk >> 20], 1u);
        csr[p] = (int)(pk & 0xFFFFFu);
    }
}

// ---------------- fused agg1 + gemm2 (round-10 proven) ---------------------
__global__ __launch_bounds__(256) void agg_gemm_kernel(
    const int* __restrict__ csr, const unsigned* __restrict__ row,
    const unsigned short* __restrict__ hs1, const float* __restrict__ dinv,
    const float* __restrict__ bias, const unsigned short* __restrict__ w2s,
    unsigned short* __restrict__ hs2, int N) {
    __shared__ short sA[2048];   // 16 rows x 128 ch, frag order
    const int t = threadIdx.x;
    const int i0 = blockIdx.x * 16;
    const int i = i0 + (t >> 4);   // node
    const int l = t & 15;          // channel-lane: ch [8l, 8l+8)

    float s0 = 0.f, s1 = 0.f, s2 = 0.f, s3 = 0.f,
          s4 = 0.f, s5 = 0.f, s6 = 0.f, s7 = 0.f;
    if (i < N) {
        const int co = 8 * l;
        {
            const float wsf = dinv[i];
            uint4 u = *(const uint4*)(hs1 + (size_t)i * 128 + co);   // self
            s0 += wsf * __uint_as_float(u.x << 16);
            s1 += wsf * __uint_as_float(u.x & 0xffff0000u);
            s2 += wsf * __uint_as_float(u.y << 16);
            s3 += wsf * __uint_as_float(u.y & 0xffff0000u);
            s4 += wsf * __uint_as_float(u.z << 16);
            s5 += wsf * __uint_as_float(u.z & 0xffff0000u);
            s6 += wsf * __uint_as_float(u.w << 16);
            s7 += wsf * __uint_as_float(u.w & 0xffff0000u);
        }
        const int rs = (int)row[i], re = (int)row[i + 1];
        for (int e0 = rs; e0 < re; e0 += 16) {
            int idx = (e0 + l < re) ? csr[e0 + l] : 0;
            const int cnt = min(16, re - e0);
#pragma unroll 4
            for (int j = 0; j < cnt; j++) {
                int s = __shfl(idx, j, 16);
                const float wsr = dinv[s];
                uint4 u = *(const uint4*)(hs1 + (size_t)s * 128 + co);
                s0 += wsr * __uint_as_float(u.x << 16);
                s1 += wsr * __uint_as_float(u.x & 0xffff0000u);
                s2 += wsr * __uint_as_float(u.y << 16);
                s3 += wsr * __uint_as_float(u.y & 0xffff0000u);
                s4 += wsr * __uint_as_float(u.z << 16);
                s5 += wsr * __uint_as_float(u.z & 0xffff0000u);
                s6 += wsr * __uint_as_float(u.w << 16);
                s7 += wsr * __uint_as_float(u.w & 0xffff0000u);
            }
        }
        const float sc = dinv[i];
        const int co2 = 8 * l;
        const float4 ba = *(const float4*)(bias + co2);
        const float4 bb = *(const float4*)(bias + co2 + 4);
        s0 = fmaxf(s0 * sc + ba.x, 0.f); s1 = fmaxf(s1 * sc + ba.y, 0.f);
        s2 = fmaxf(s2 * sc + ba.z, 0.f); s3 = fmaxf(s3 * sc + ba.w, 0.f);
        s4 = fmaxf(s4 * sc + bb.x, 0.f); s5 = fmaxf(s5 * sc + bb.y, 0.f);
        s6 = fmaxf(s6 * sc + bb.z, 0.f); s7 = fmaxf(s7 * sc + bb.w, 0.f);
    } else {
        s0 = s1 = s2 = s3 = s4 = s5 = s6 = s7 = 0.f;
    }
    // ---- pack bf16 + store to LDS in A-frag order ----
    {
        uint4 u;
        u.x = (unsigned)f2bf(s0) | ((unsigned)f2bf(s1) << 16);
        u.y = (unsigned)f2bf(s2) | ((unsigned)f2bf(s3) << 16);
        u.z = (unsigned)f2bf(s4) | ((unsigned)f2bf(s5) << 16);
        u.w = (unsigned)f2bf(s6) | ((unsigned)f2bf(s7) << 16);
        int off = (l >> 2) * 512 + (((t >> 4) * 4 + (l & 3)) * 8);
        *(uint4*)(sA + off) = u;
    }
    __syncthreads();

    // ---- gemm phase: wave w computes n-tile nt=w (cols [16w,16w+16)) ----
    const int w = t >> 6, lane = t & 63;
    const int m = lane & 15, q = lane >> 4;
    const int fb = (m * 4 + q) * 8;
    f32x4 acc = (f32x4){0.f, 0.f, 0.f, 0.f};
#pragma unroll
    for (int ks = 0; ks < 4; ks++) {
        bf16x8 a = *(const bf16x8*)(sA + ks * 512 + fb);
        bf16x8 b = *(const bf16x8*)(w2s + (w * 4 + ks) * 512 + fb);
        acc = __builtin_amdgcn_mfma_f32_16x16x32_bf16(a, b, acc, 0, 0, 0);
    }
    // D layout: row = q*4+r (node within tile), col = w*16 + m
#pragma unroll
    for (int r = 0; r < 4; r++) {
        int rr = i0 + q * 4 + r;
        if (rr < N) {
            float s = dinv[rr];
            hs2[(size_t)rr * 64 + w * 16 + m] = f2bf(acc[r] * s);
        }
    }
}

// ---------------- agg2 (round-10 proven + NT store of final output) --------
__global__ __launch_bounds__(256) void agg2_kernel(
    const int* __restrict__ csr, const unsigned* __restrict__ row,
    const unsigned short* __restrict__ hsb, const float* __restrict__ dinv,
    const float* __restrict__ bias, float* __restrict__ outv, int N) {
    constexpr int C = 64, LPN = 8;
    const int tid = blockIdx.x * 256 + threadIdx.x;
    const int i = tid / LPN;
    const int l = tid % LPN;
    if (i >= N) return;

    const int co = 8 * l;
    float s0 = 0.f, s1 = 0.f, s2 = 0.f, s3 = 0.f,
          s4 = 0.f, s5 = 0.f, s6 = 0.f, s7 = 0.f;
    {
        uint4 u = *(const uint4*)(hsb + (size_t)i * C + co);   // self
        s0 += __uint_as_float(u.x << 16); s1 += __uint_as_float(u.x & 0xffff0000u);
        s2 += __uint_as_float(u.y << 16); s3 += __uint_as_float(u.y & 0xffff0000u);
        s4 += __uint_as_float(u.z << 16); s5 += __uint_as_float(u.z & 0xffff0000u);
        s6 += __uint_as_float(u.w << 16); s7 += __uint_as_float(u.w & 0xffff0000u);
    }

    const int rs = (int)row[i], re = (int)row[i + 1];
    for (int e0 = rs; e0 < re; e0 += LPN) {
        int idx = (e0 + l < re) ? csr[e0 + l] : 0;
        const int cnt = min(LPN, re - e0);
#pragma unroll 4
        for (int j = 0; j < cnt; j++) {
            int s = __shfl(idx, j, LPN);
            uint4 u = *(const uint4*)(hsb + (size_t)s * C + co);
            s0 += __uint_as_float(u.x << 16); s1 += __uint_as_float(u.x & 0xffff0000u);
            s2 += __uint_as_float(u.y << 16); s3 += __uint_as_float(u.y & 0xffff0000u);
            s4 += __uint_as_float(u.z << 16); s5 += __uint_as_float(u.z & 0xffff0000u);
            s6 += __uint_as_float(u.w << 16); s7 += __uint_as_float(u.w & 0xffff0000u);
        }
    }

    const float sc = dinv[i];
    const float4 ba = *(const float4*)(bias + co);
    const float4 bb = *(const float4*)(bias + co + 4);
    f32x4 a = (f32x4){s0 * sc + ba.x, s1 * sc + ba.y,
                      s2 * sc + ba.z, s3 * sc + ba.w};
    f32x4 b = (f32x4){s4 * sc + bb.x, s5 * sc + bb.y,
                      s6 * sc + bb.z, s7 * sc + bb.w};
    // NT stores: d_out is write-once, never re-read — keep hs2 resident in L2
    float* op = outv + (size_t)i * C + co;
    __builtin_nontemporal_store(a, (f32x4*)op);
    __builtin_nontemporal_store(b, (f32x4*)(op + 4));
}

// ---------------- launch ----------------
extern "C" void kernel_launch(void* const* d_in, const int* in_sizes, int n_in,
                              void* d_out, int out_size, void* d_ws,
                              size_t ws_size, hipStream_t stream) {
    const float* x  = (const float*)d_in[0];
    const float* W1 = (const float*)d_in[1];
    const float* b1 = (const float*)d_in[2];
    const float* W2 = (const float*)d_in[3];
    const float* b2 = (const float*)d_in[4];
    const unsigned* ew = (const unsigned*)d_in[5];
    const int E = in_sizes[5] / 2;        // 1,600,000
    const int N = in_sizes[0] / 128;      // 100,000
    const int nbuck = (N + BWIDTH - 1) >> BSHIFT;   // 782

    char* ws = (char*)d_ws;
    unsigned* row  = (unsigned*)(ws + OFF_ROW);
    unsigned* ccnt = (unsigned*)(ws + OFF_CCNT);
    unsigned* coff = (unsigned*)(ws + OFF_COFF);
    float* dinv    = (float*)(ws + OFF_DINV);
    int* csr       = (int*)(ws + OFF_CSR);
    unsigned short* hs1  = (unsigned short*)(ws + OFF_HS1);
    unsigned short* hs2  = (unsigned short*)(ws + OFF_HS2);
    unsigned* h2   = (unsigned*)(ws + OFF_H2);
    unsigned short* w1s  = (unsigned short*)(ws + OFF_W1S);
    unsigned short* w2s  = (unsigned short*)(ws + OFF_W2S);
    unsigned* part = (unsigned*)(ws + OFF_PART);

    hipMemsetAsync(ccnt, 0, (size_t)(nbuck + 1) * 4, stream);

    // ---- CSR build + W prep; gemm1 fused into the bucket dispatch ----
    hist_wprep_kernel<<<NPART + 2, 1024, 0, stream>>>(ew, ccnt, h2, E, nbuck,
                                                      W1, W2, w1s, w2s);
    scanoff_kernel<<<nbuck, NPART, 0, stream>>>(ccnt, coff, h2, nbuck);
    partition_kernel<<<NPART, 1024, 0, stream>>>(ew, h2, part, E, nbuck);
    bucket_gemm_kernel<<<nbuck + (N + 127) / 128, 256, 0, stream>>>(
        part, coff, row, dinv, csr, N, nbuck, x, w1s, hs1);

    // ---- fused agg1 + gemm2 ----
    agg_gemm_kernel<<<(N + 15) / 16, 256, 0, stream>>>(
        csr, row, hs1, dinv, b1, w2s, hs2, N);

    // ---- agg2 (final, fp32 out, NT stores) ----
    agg2_kernel<<<(N * 8 + 255) / 256, 256, 0, stream>>>(
        csr, row, hs2, dinv, b2, (float*)d_out, N);
}